// Round 8
// baseline (483.525 us; speedup 1.0000x reference)
//
#include <hip/hip_runtime.h>

#define TSEQ   2048
#define CDIM   2048
#define NHEAD  16
#define DHEAD  128
#define NBATCH 2
#define MROWS  (NBATCH * TSEQ)   // 4096
#define WIN    512

typedef unsigned short u16;
typedef __attribute__((ext_vector_type(8))) short short8;   // 8 bf16 (4 VGPRs)
typedef __attribute__((ext_vector_type(4))) float f32x4;
typedef __attribute__((ext_vector_type(16))) float f32x16;
typedef __attribute__((ext_vector_type(4))) u16 u16x4;
typedef __attribute__((ext_vector_type(8))) u16 u16x8;

__device__ __forceinline__ void gload_lds16(const void* g, void* l) {
  __builtin_amdgcn_global_load_lds(
      (const __attribute__((address_space(1))) unsigned int*)g,
      (__attribute__((address_space(3))) unsigned int*)l, 16, 0, 0);
}

__device__ __forceinline__ u16 f2bf(float f) {
  unsigned u = __float_as_uint(f);
  u += 0x7fffu + ((u >> 16) & 1u);   // RNE
  return (u16)(u >> 16);
}
__device__ __forceinline__ float bf2f(u16 h) {
  return __uint_as_float((unsigned)h << 16);
}

// ---------------------------------------------------------------------------
// Weight transpose + fp32->bf16 (z<4): WT[n*C + k] = bf16(W[k*C + n]).
// z==4 plane: bulk convert x fp32 -> bf16 (2 float4 per thread).
// ---------------------------------------------------------------------------
__global__ __launch_bounds__(256) void transpose_kernel(
    const float* __restrict__ i0, const float* __restrict__ i1,
    const float* __restrict__ i2, const float* __restrict__ i3,
    u16* __restrict__ o0, u16* __restrict__ o1,
    u16* __restrict__ o2, u16* __restrict__ o3,
    const float* __restrict__ xin, u16* __restrict__ xout) {
  const int z = blockIdx.z;
  if (z == 4) {
    const int tf = threadIdx.y * 32 + threadIdx.x;
    const int base = (blockIdx.y * 64 + blockIdx.x) * 512 + tf * 2;
#pragma unroll
    for (int c = 0; c < 2; ++c) {
      const float4 v = ((const float4*)xin)[base + c];
      u16x4 ov;
      ov[0] = f2bf(v.x); ov[1] = f2bf(v.y); ov[2] = f2bf(v.z); ov[3] = f2bf(v.w);
      ((u16x4*)xout)[base + c] = ov;
    }
    return;
  }
  const float* in = (z == 0) ? i0 : (z == 1) ? i1 : (z == 2) ? i2 : i3;
  u16*       out = (z == 0) ? o0 : (z == 1) ? o1 : (z == 2) ? o2 : o3;
  __shared__ u16 tile[32][33];
  const int x  = blockIdx.x * 32 + threadIdx.x;
  const int y0 = blockIdx.y * 32 + threadIdx.y;
#pragma unroll
  for (int i = 0; i < 32; i += 8)
    tile[threadIdx.y + i][threadIdx.x] = f2bf(in[(size_t)(y0 + i) * CDIM + x]);
  __syncthreads();
  const int x2 = blockIdx.y * 32 + threadIdx.x;
  const int y2 = blockIdx.x * 32 + threadIdx.y;
#pragma unroll
  for (int i = 0; i < 32; i += 8)
    out[(size_t)(y2 + i) * CDIM + x2] = tile[threadIdx.x][threadIdx.y + i];
}

// ---------------------------------------------------------------------------
// RoPE tables: ct/st[t*64 + i] = cos/sin(t * 10000^(-i/64))
// ---------------------------------------------------------------------------
__global__ __launch_bounds__(256) void rope_table_kernel(float* __restrict__ ct,
                                                         float* __restrict__ st) {
  const int idx = blockIdx.x * 256 + threadIdx.x;   // < TSEQ*64
  const int t = idx >> 6, i = idx & 63;
  const float inv = exp2f(-(float)i * (13.287712379549449f / 64.0f)); // log2(10000)/64
  const float f = (float)t * inv;
  ct[idx] = cosf(f);
  st[idx] = sinf(f);
}

// ---------------------------------------------------------------------------
// RoPE apply, in place on q (y=0) / k (y=1). rotate-half pairs (i, i+64).
// ---------------------------------------------------------------------------
__global__ __launch_bounds__(256) void rope_apply_kernel(
    u16* __restrict__ q, u16* __restrict__ k,
    const float* __restrict__ ct, const float* __restrict__ st) {
  const int flat = blockIdx.x * 256 + threadIdx.x;  // < B*T*H*64 = 2^22
  u16* X = (blockIdx.y == 0) ? q : k;
  const int i = flat & 63;
  const int h = (flat >> 6) & (NHEAD - 1);
  const int t = (flat >> 10) & (TSEQ - 1);
  const int b = flat >> 21;
  const size_t base = ((size_t)(b * TSEQ + t)) * CDIM + h * DHEAD + i;
  const float u1 = bf2f(X[base]), u2 = bf2f(X[base + 64]);
  const float c = ct[t * 64 + i], s = st[t * 64 + i];
  X[base]      = f2bf(u1 * c - u2 * s);
  X[base + 64] = f2bf(u1 * s + u2 * c);
}

// ---------------------------------------------------------------------------
// BK=64 GEMM: C[M=4096, N=2048] = A[M,K=2048] * Bt[N,K]^T, bf16 internal.
// 128x128 tile, 4 waves, 16x16x32 MFMA, global_load_lds width 16.
// XOR-swizzled LDS layout. Grid (n, z, m).
// Epilogues: OF!=null -> fp32 natural; z==vz -> bf16 vT; else bf16 natural.
// ---------------------------------------------------------------------------
__global__ __launch_bounds__(256, 4) void gemm_bt_kernel(
    const u16* __restrict__ A,
    const u16* __restrict__ B0, const u16* __restrict__ B1, const u16* __restrict__ B2,
    u16* __restrict__ O0, u16* __restrict__ O1, u16* __restrict__ O2,
    int vz, float* __restrict__ OF) {
  const int z = blockIdx.y;
  const u16* Bt = (z == 0) ? B0 : (z == 1) ? B1 : B2;
  u16*       O  = (z == 0) ? O0 : (z == 1) ? O1 : O2;

  __shared__ u16 As[128 * 64];   // 16 KB, swizzled row-major
  __shared__ u16 Bs[128 * 64];   // 16 KB

  const int tid  = threadIdx.x;
  const int wave = tid >> 6;
  const int lane = tid & 63;
  const int quad = lane >> 4;
  const int l15  = lane & 15;

  const int bm = blockIdx.z * 128;
  const int bn = blockIdx.x * 128;

  const int rlo = lane >> 3;                     // 0..7
  const int swb = ((lane & 7) + rlo) & 7;        // swizzled source block
  const u16* Ag = A  + (size_t)(bm + wave * 32 + rlo) * CDIM + swb * 8;
  const u16* Bg = Bt + (size_t)(bn + wave * 32 + rlo) * CDIM + swb * 8;
  u16* AsW = As + wave * 2048 + lane * 8;
  u16* BsW = Bs + wave * 2048 + lane * 8;

  const f32x4 zero4 = {0.f, 0.f, 0.f, 0.f};
  f32x4 acc[4][4];
#pragma unroll
  for (int mt = 0; mt < 4; ++mt)
#pragma unroll
    for (int nt = 0; nt < 4; ++nt) acc[mt][nt] = zero4;

  const int mh = (wave >> 1) * 64;
  const int nh = (wave & 1) * 64;

  const int off0 = ((quad - l15) & 7) * 8;       // ks = 0
  const int off1 = off0 ^ 32;                    // ks = 1

  for (int kb = 0; kb < CDIM; kb += 64) {
#pragma unroll
    for (int g = 0; g < 4; ++g) {
      gload_lds16(Ag + kb + (size_t)g * 8 * CDIM, AsW + g * 512);
      gload_lds16(Bg + kb + (size_t)g * 8 * CDIM, BsW + g * 512);
    }
    __syncthreads();

#pragma unroll
    for (int ks = 0; ks < 2; ++ks) {
      const int fo = ks ? off1 : off0;
      short8 af[4], bfr[4];
#pragma unroll
      for (int t = 0; t < 4; ++t) {
        af[t]  = *(const short8*)(As + (mh + t * 16 + l15) * 64 + fo);
        bfr[t] = *(const short8*)(Bs + (nh + t * 16 + l15) * 64 + fo);
      }
#pragma unroll
      for (int mt = 0; mt < 4; ++mt)
#pragma unroll
        for (int nt = 0; nt < 4; ++nt)
          acc[mt][nt] = __builtin_amdgcn_mfma_f32_16x16x32_bf16(af[mt], bfr[nt],
                                                                acc[mt][nt], 0, 0, 0);
    }
    __syncthreads();
  }

  if (OF != nullptr) {
#pragma unroll
    for (int mt = 0; mt < 4; ++mt) {
      const int row0 = bm + mh + mt * 16 + quad * 4;
#pragma unroll
      for (int nt = 0; nt < 4; ++nt) {
        const int col = bn + nh + nt * 16 + l15;
#pragma unroll
        for (int r = 0; r < 4; ++r)
          OF[(size_t)(row0 + r) * CDIM + col] = acc[mt][nt][r];
      }
    }
  } else if (z != vz) {
#pragma unroll
    for (int mt = 0; mt < 4; ++mt) {
      const int row0 = bm + mh + mt * 16 + quad * 4;
#pragma unroll
      for (int nt = 0; nt < 4; ++nt) {
        const int col = bn + nh + nt * 16 + l15;
#pragma unroll
        for (int r = 0; r < 4; ++r)
          O[(size_t)(row0 + r) * CDIM + col] = f2bf(acc[mt][nt][r]);
      }
    }
  } else {
    // v epilogue: O = vT[(b*H + head)*D + d][t]; packed 8B store
    const int head = bn >> 7;
#pragma unroll
    for (int mt = 0; mt < 4; ++mt) {
      const int gm0 = bm + mh + mt * 16 + quad * 4;
      const int b  = gm0 >> 11;
      const int t0 = gm0 & (TSEQ - 1);
#pragma unroll
      for (int nt = 0; nt < 4; ++nt) {
        const int d = nh + nt * 16 + l15;
        u16x4 pk;
#pragma unroll
        for (int r = 0; r < 4; ++r) pk[r] = f2bf(acc[mt][nt][r]);
        *(u16x4*)(O + ((size_t)((b * NHEAD + head) * DHEAD + d)) * TSEQ + t0) = pk;
      }
    }
  }
}

// ---------------------------------------------------------------------------
// Flash attention, S^T formulation, 32x32x16 MFMA, in-register softmax.
// R8 = R5's even/odd KV split + R7's lean body (no spill this time):
// 512 threads = 8 waves. Waves 0-3 (half 0) process even-indexed active
// key tiles, waves 4-7 odd ones, each half on its own double-buffered
// 32 KB LDS region. NO duplicated work (R6's tax), NO global partials
// (R4's tax). Grid 512 x 8 waves = 4 waves/SIMD (R7 had 2).
// Fixed-shift softmax -> (O,l) additive; combine = one 64 KB LDS exchange
// at the end (half-1 writes fp32 O^T, half-0 adds+normalizes+stores).
// Register budget: oacc[4]=64 + qf=32 + transients ~20 = ~105 < 128, so
// __launch_bounds__(512,4) does NOT spill (R5 failed this with reg-staging;
// R7 moved staging to gload_lds w/ pre-swizzled global source -> lean).
// Kept: XCD remap (K/V L2-resident), XOR chunk swizzles, tile-skip remap.
// LDS 64.5 KB, 2 blocks/CU.
// ---------------------------------------------------------------------------
__global__ __launch_bounds__(512, 4) void attn_kernel(
    const u16* __restrict__ q, const u16* __restrict__ k,
    const u16* __restrict__ vT, u16* __restrict__ o) {
  // [ks: half][buf][32][128] = 32 KB][vs: half][buf][128][32] = 32 KB]
  // combine phase aliases the whole 64 KB as float cb[4][128][32].
  __shared__ u16 smem[32768];
  __shared__ float lrLds[4 * 32];

  const int tid  = threadIdx.x;        // 0..511
  const int wave = tid >> 6;           // 0..7
  const int half = wave >> 2;          // tile parity this wave serves
  const int w3   = wave & 3;           // q-subtile
  const int lane = tid & 63;
  const int hi   = lane >> 5;          // k-half select in 32x32x16 fragments
  const int l31  = lane & 31;

  // XCD-aware remap: xcd = flat%8 owns 4 heads x 16 q-blocks
  // -> 4 MB K/V working set per XCD = one L2.
  const int flat = blockIdx.y * 16 + blockIdx.x;   // [0,512)
  const int qb   = (flat >> 3) & 15;
  const int bh   = (flat & 7) * 4 + (flat >> 7);   // b*16 + h
  const int b    = bh >> 4;
  const int h    = bh & 15;
  const int qw0  = qb * 128 + w3 * 32;
  const int qi   = qw0 + l31;          // this lane's q row (col of S^T)

  u16* ksH = smem + half * 8192;            // [buf][key 32][chan 128]
  u16* vsH = smem + 16384 + half * 8192;    // [buf][d 128][key 32]

  // Q B-fragments: qf[s] = Q[qi][s*16 + hi*8 .. +8]
  short8 qf[8];
  {
    const u16* qrow = q + ((size_t)(b * TSEQ + qi)) * CDIM + h * DHEAD + hi * 8;
#pragma unroll
    for (int s = 0; s < 8; ++s) qf[s] = *(const short8*)(qrow + s * 16);
  }

  f32x16 oacc[4];   // [dt]: O^T[d = dt*32 + (r&3)+8*(r>>2)+4*hi][q = qi]
#pragma unroll
  for (int dt = 0; dt < 4; ++dt)
#pragma unroll
    for (int r = 0; r < 16; ++r) oacc[dt][r] = 0.f;
  float lrow = 0.f;

  const u16* kbase = k + ((size_t)(b * TSEQ)) * CDIM + h * DHEAD;
  const u16* vbase = vT + ((size_t)bh) * DHEAD * TSEQ;
  const float SC  = 0.08838834764831845f * 1.4426950408889634f; // 1/sqrt(128)*log2e
  const float MSH = 12.0f;   // fixed softmax shift (log2 domain)

  // remap out the fully-block-masked 32-key tiles: t in [4qb-12, 4qb-1]
  int tlo = 4 * qb - 12; if (tlo < 0) tlo = 0;
  int nskip = (4 * qb - 1) - tlo + 1; if (nskip < 0) nskip = 0;
  const int nact  = 64 - nskip;        // active tiles, 52..64
  const int nIter = (nact + 1) >> 1;   // barrier steps per half
  auto jof = [&](int a) { return ((a < tlo) ? a : a + nskip) * 32; };

  // gload_lds staging (per half-group: 4 waves x (2 K + 2 V) gloads/tile).
  // LDS dest linear (base + lane*16); global SOURCE pre-swizzled so that
  // LDS[row][c] = X[row][c ^ f(row)] (16B chunks), matching the reads.
  const int kr0 = w3 * 8 + (lane >> 4);
  const int kc  = lane & 15;
  const u16* kgp0 = kbase + (size_t)kr0 * CDIM + ((kc ^ (kr0 & 7)) * 8);
  const u16* kgp1 = kbase + (size_t)(kr0 + 4) * CDIM + ((kc ^ ((kr0 + 4) & 7)) * 8);
  const int vr0 = w3 * 32 + (lane >> 2);
  const int vc  = lane & 3;
  const u16* vgp0 = vbase + (size_t)vr0 * TSEQ + ((vc ^ ((vr0 >> 2) & 3)) * 8);
  const u16* vgp1 = vbase + (size_t)(vr0 + 16) * TSEQ + ((vc ^ (((vr0 + 16) >> 2) & 3)) * 8);
  u16* ksw0 = ksH + (w3 * 8) * 128 + lane * 8;        // buf0; buf1 = +4096
  u16* ksw1 = ksH + (w3 * 8 + 4) * 128 + lane * 8;
  u16* vsw0 = vsH + (w3 * 32) * 32 + lane * 8;
  u16* vsw1 = vsH + (w3 * 32 + 16) * 32 + lane * 8;

  auto stage = [&](int j, int buf) {
    const int off = buf * 4096;
    gload_lds16(kgp0 + (size_t)j * CDIM, ksw0 + off);
    gload_lds16(kgp1 + (size_t)j * CDIM, ksw1 + off);
    gload_lds16(vgp0 + j, vsw0 + off);
    gload_lds16(vgp1 + j, vsw1 + off);
  };

  // prologue: each half stages its first tile (a = half) into buffer 0
  stage(jof(half), 0);
  __syncthreads();

  for (int it = 0; it < nIter; ++it) {
    const int p = it & 1;
    const int a = 2 * it + half;      // this half's active index
    const bool va = a < nact;
    const bool vn = (a + 2) < nact;

    // issue this half's next tile into the other buffer (hidden under
    // compute; the barrier at loop end drains vmcnt before reads)
    if (vn) stage(jof(a + 2), 1 - p);

    const u16* ksp = ksH + p * 4096;
    const u16* vsp = vsH + p * 4096;

    if (va) {
      const int j0 = jof(a);
      const bool wskip = (j0 + 31 <= qw0) && (j0 >= qw0 + 31 - (WIN - 1));
      if (!wskip) {
        // S^T = K * Q^T: one 32x32 tile, K=128 over 8 MFMAs.
        f32x16 sf;
#pragma unroll
        for (int r = 0; r < 16; ++r) sf[r] = 0.f;
#pragma unroll
        for (int s = 0; s < 8; ++s) {
          const short8 kf =
              *(const short8*)(ksp + l31 * 128 + (((s * 2 + hi) ^ (l31 & 7)) * 8));
          sf = __builtin_amdgcn_mfma_f32_32x32x16_bf16(kf, qf[s], sf, 0, 0, 0);
        }

        // softmax numerator (+ mask only on band-edge tiles, wave-uniform).
        // element r: key = j0 + (r&3) + 8*(r>>2) + 4*hi, q = qi.
        float pe[16];
        const bool hasMask = (qw0 + 31 >= j0) && (qw0 <= j0 + 31 + (WIN - 1));
        if (hasMask) {
#pragma unroll
          for (int r = 0; r < 16; ++r) {
            const int kj = j0 + (r & 3) + 8 * (r >> 2) + 4 * hi;
            const float e = exp2f(fmaf(sf[r], SC, -MSH));
            pe[r] = ((unsigned)(qi - kj) < (unsigned)WIN) ? 0.f : e;
          }
        } else {
#pragma unroll
          for (int r = 0; r < 16; ++r) pe[r] = exp2f(fmaf(sf[r], SC, -MSH));
        }
#pragma unroll
        for (int r = 0; r < 16; ++r) lrow += pe[r];

        // P -> bf16 PV B-fragments, fully in registers:
        // 8x v_cvt_pk_bf16_f32 + 4x v_permlane32_swap_b32.
        int D0, D1, D2, D3, D4, D5, D6, D7;
        asm("v_cvt_pk_bf16_f32 %0, %1, %2" : "=v"(D0) : "v"(pe[0]),  "v"(pe[1]));
        asm("v_cvt_pk_bf16_f32 %0, %1, %2" : "=v"(D1) : "v"(pe[2]),  "v"(pe[3]));
        asm("v_cvt_pk_bf16_f32 %0, %1, %2" : "=v"(D2) : "v"(pe[4]),  "v"(pe[5]));
        asm("v_cvt_pk_bf16_f32 %0, %1, %2" : "=v"(D3) : "v"(pe[6]),  "v"(pe[7]));
        asm("v_cvt_pk_bf16_f32 %0, %1, %2" : "=v"(D4) : "v"(pe[8]),  "v"(pe[9]));
        asm("v_cvt_pk_bf16_f32 %0, %1, %2" : "=v"(D5) : "v"(pe[10]), "v"(pe[11]));
        asm("v_cvt_pk_bf16_f32 %0, %1, %2" : "=v"(D6) : "v"(pe[12]), "v"(pe[13]));
        asm("v_cvt_pk_bf16_f32 %0, %1, %2" : "=v"(D7) : "v"(pe[14]), "v"(pe[15]));
        asm("v_permlane32_swap_b32 %0, %1" : "+v"(D0), "+v"(D2));
        asm("v_permlane32_swap_b32 %0, %1" : "+v"(D1), "+v"(D3));
        asm("v_permlane32_swap_b32 %0, %1" : "+v"(D4), "+v"(D6));
        asm("v_permlane32_swap_b32 %0, %1" : "+v"(D5), "+v"(D7));

        union { int i[4]; short8 s8; } u0, u1;
        u0.i[0] = D0; u0.i[1] = D1; u0.i[2] = D2; u0.i[3] = D3;
        u1.i[0] = D4; u1.i[1] = D5; u1.i[2] = D6; u1.i[3] = D7;
        const short8 pf0 = u0.s8;   // B[k = keys 0..15][q]
        const short8 pf1 = u1.s8;   // B[k = keys 16..31][q]

        // O^T += V^T * P^T  (A = V^T rows d, 4 d-tiles x 2 k-steps)
#pragma unroll
        for (int dt = 0; dt < 4; ++dt) {
          const int row = dt * 32 + l31;
          const short8 vf0 =
              *(const short8*)(vsp + row * 32 + (((0 + hi) ^ ((l31 >> 2) & 3)) * 8));
          const short8 vf1 =
              *(const short8*)(vsp + row * 32 + (((2 + hi) ^ ((l31 >> 2) & 3)) * 8));
          oacc[dt] = __builtin_amdgcn_mfma_f32_32x32x16_bf16(vf0, pf0, oacc[dt], 0, 0, 0);
          oacc[dt] = __builtin_amdgcn_mfma_f32_32x32x16_bf16(vf1, pf1, oacc[dt], 0, 0, 0);
        }
      }
    }

    __syncthreads();   // drains vmcnt (prefetch landed) + frees buf p
  }

  // lrow: lanes hi=0/1 hold complementary key subsets for the same q
  lrow += __shfl_xor(lrow, 32, 64);

  // combine halves through LDS (aliases staging; all tile reads completed
  // at the loop's final barrier). half-1 publishes, half-0 merges+stores.
  float* cb = (float*)smem;   // [w3][d 128][q 32] fp32 = 64 KB
  if (half == 1) {
    if (hi == 0) lrLds[w3 * 32 + l31] = lrow;
#pragma unroll
    for (int dt = 0; dt < 4; ++dt)
#pragma unroll
      for (int r = 0; r < 16; ++r) {
        const int d = dt * 32 + 8 * (r >> 2) + 4 * hi + (r & 3);
        cb[((w3 << 7) + d) * 32 + l31] = oacc[dt][r];
      }
  }
  __syncthreads();
  if (half == 0) {
    const float inv = 1.0f / (lrow + lrLds[w3 * 32 + l31]);
    u16* obase = o + ((size_t)(b * TSEQ + qi)) * CDIM + h * DHEAD;
#pragma unroll
    for (int dt = 0; dt < 4; ++dt)
#pragma unroll
      for (int a2 = 0; a2 < 4; ++a2) {
        u16x4 pkd;
#pragma unroll
        for (int r = 0; r < 4; ++r) {
          const int d = dt * 32 + 8 * a2 + 4 * hi + r;
          const float v = oacc[dt][a2 * 4 + r] + cb[((w3 << 7) + d) * 32 + l31];
          pkd[r] = f2bf(v * inv);
        }
        *(u16x4*)(obase + dt * 32 + a2 * 8 + hi * 4) = pkd;
      }
  }
}

// ---------------------------------------------------------------------------
extern "C" void kernel_launch(void* const* d_in, const int* in_sizes, int n_in,
                              void* d_out, int out_size, void* d_ws, size_t ws_size,
                              hipStream_t stream) {
  (void)in_sizes; (void)n_in; (void)out_size; (void)ws_size;
  const float* x  = (const float*)d_in[0];
  const float* Wq = (const float*)d_in[1];
  const float* Wk = (const float*)d_in[2];
  const float* Wv = (const float*)d_in[3];
  const float* Wo = (const float*)d_in[4];
  float* out = (float*)d_out;

  char* ws = (char*)d_ws;
  const size_t WT = (size_t)CDIM * CDIM * sizeof(u16);   // 8 MiB
  const size_t QS = (size_t)MROWS * CDIM * sizeof(u16);  // 16 MiB
  u16* WqT = (u16*)(ws + 0 * WT);
  u16* WkT = (u16*)(ws + 1 * WT);
  u16* WvT = (u16*)(ws + 2 * WT);
  u16* WoT = (u16*)(ws + 3 * WT);
  u16* xb  = (u16*)(ws + 4 * WT);
  u16* qb  = (u16*)(ws + 4 * WT + 1 * QS);
  u16* kb  = (u16*)(ws + 4 * WT + 2 * QS);
  u16* vTb = (u16*)(ws + 4 * WT + 3 * QS);
  u16* ob  = (u16*)(ws + 4 * WT + 4 * QS);
  float* ct = (float*)(ws + 4 * WT + 5 * QS);
  float* st = ct + TSEQ * 64;

  transpose_kernel<<<dim3(64, 64, 5), dim3(32, 8), 0, stream>>>(
      Wq, Wk, Wv, Wo, WqT, WkT, WvT, WoT, x, xb);
  rope_table_kernel<<<dim3(TSEQ * 64 / 256), 256, 0, stream>>>(ct, st);
  gemm_bt_kernel<<<dim3(16, 3, 32), 256, 0, stream>>>(
      xb, WqT, WkT, WvT, qb, kb, vTb, 2, nullptr);
  rope_apply_kernel<<<dim3(16384, 2), 256, 0, stream>>>(qb, kb, ct, st);
  attn_kernel<<<dim3(16, 32), 512, 0, stream>>>(qb, kb, vTb, ob);
  gemm_bt_kernel<<<dim3(16, 1, 32), 256, 0, stream>>>(
      ob, WoT, WoT, WoT, nullptr, nullptr, nullptr, -1, out);
}

// Round 9
// 382.185 us; speedup vs baseline: 1.2652x; 1.2652x over previous
//
#include <hip/hip_runtime.h>

#define TSEQ   2048
#define CDIM   2048
#define NHEAD  16
#define DHEAD  128
#define NBATCH 2
#define MROWS  (NBATCH * TSEQ)   // 4096
#define WIN    512

typedef unsigned short u16;
typedef __attribute__((ext_vector_type(8))) short short8;   // 8 bf16 (4 VGPRs)
typedef __attribute__((ext_vector_type(4))) float f32x4;
typedef __attribute__((ext_vector_type(16))) float f32x16;
typedef __attribute__((ext_vector_type(4))) u16 u16x4;
typedef __attribute__((ext_vector_type(8))) u16 u16x8;

__device__ __forceinline__ void gload_lds16(const void* g, void* l) {
  __builtin_amdgcn_global_load_lds(
      (const __attribute__((address_space(1))) unsigned int*)g,
      (__attribute__((address_space(3))) unsigned int*)l, 16, 0, 0);
}

__device__ __forceinline__ u16 f2bf(float f) {
  unsigned u = __float_as_uint(f);
  u += 0x7fffu + ((u >> 16) & 1u);   // RNE
  return (u16)(u >> 16);
}
__device__ __forceinline__ float bf2f(u16 h) {
  return __uint_as_float((unsigned)h << 16);
}

// ---------------------------------------------------------------------------
// Weight transpose + fp32->bf16 (z<4): WT[n*C + k] = bf16(W[k*C + n]).
// z==4 plane: bulk convert x fp32 -> bf16 (2 float4 per thread).
// ---------------------------------------------------------------------------
__global__ __launch_bounds__(256) void transpose_kernel(
    const float* __restrict__ i0, const float* __restrict__ i1,
    const float* __restrict__ i2, const float* __restrict__ i3,
    u16* __restrict__ o0, u16* __restrict__ o1,
    u16* __restrict__ o2, u16* __restrict__ o3,
    const float* __restrict__ xin, u16* __restrict__ xout) {
  const int z = blockIdx.z;
  if (z == 4) {
    const int tf = threadIdx.y * 32 + threadIdx.x;
    const int base = (blockIdx.y * 64 + blockIdx.x) * 512 + tf * 2;
#pragma unroll
    for (int c = 0; c < 2; ++c) {
      const float4 v = ((const float4*)xin)[base + c];
      u16x4 ov;
      ov[0] = f2bf(v.x); ov[1] = f2bf(v.y); ov[2] = f2bf(v.z); ov[3] = f2bf(v.w);
      ((u16x4*)xout)[base + c] = ov;
    }
    return;
  }
  const float* in = (z == 0) ? i0 : (z == 1) ? i1 : (z == 2) ? i2 : i3;
  u16*       out = (z == 0) ? o0 : (z == 1) ? o1 : (z == 2) ? o2 : o3;
  __shared__ u16 tile[32][33];
  const int x  = blockIdx.x * 32 + threadIdx.x;
  const int y0 = blockIdx.y * 32 + threadIdx.y;
#pragma unroll
  for (int i = 0; i < 32; i += 8)
    tile[threadIdx.y + i][threadIdx.x] = f2bf(in[(size_t)(y0 + i) * CDIM + x]);
  __syncthreads();
  const int x2 = blockIdx.y * 32 + threadIdx.x;
  const int y2 = blockIdx.x * 32 + threadIdx.y;
#pragma unroll
  for (int i = 0; i < 32; i += 8)
    out[(size_t)(y2 + i) * CDIM + x2] = tile[threadIdx.x][threadIdx.y + i];
}

// ---------------------------------------------------------------------------
// RoPE tables: ct/st[t*64 + i] = cos/sin(t * 10000^(-i/64))
// ---------------------------------------------------------------------------
__global__ __launch_bounds__(256) void rope_table_kernel(float* __restrict__ ct,
                                                         float* __restrict__ st) {
  const int idx = blockIdx.x * 256 + threadIdx.x;   // < TSEQ*64
  const int t = idx >> 6, i = idx & 63;
  const float inv = exp2f(-(float)i * (13.287712379549449f / 64.0f)); // log2(10000)/64
  const float f = (float)t * inv;
  ct[idx] = cosf(f);
  st[idx] = sinf(f);
}

// ---------------------------------------------------------------------------
// RoPE apply, in place on q (y=0) / k (y=1). rotate-half pairs (i, i+64).
// ---------------------------------------------------------------------------
__global__ __launch_bounds__(256) void rope_apply_kernel(
    u16* __restrict__ q, u16* __restrict__ k,
    const float* __restrict__ ct, const float* __restrict__ st) {
  const int flat = blockIdx.x * 256 + threadIdx.x;  // < B*T*H*64 = 2^22
  u16* X = (blockIdx.y == 0) ? q : k;
  const int i = flat & 63;
  const int h = (flat >> 6) & (NHEAD - 1);
  const int t = (flat >> 10) & (TSEQ - 1);
  const int b = flat >> 21;
  const size_t base = ((size_t)(b * TSEQ + t)) * CDIM + h * DHEAD + i;
  const float u1 = bf2f(X[base]), u2 = bf2f(X[base + 64]);
  const float c = ct[t * 64 + i], s = st[t * 64 + i];
  X[base]      = f2bf(u1 * c - u2 * s);
  X[base + 64] = f2bf(u1 * s + u2 * c);
}

// ---------------------------------------------------------------------------
// BK=64 GEMM: C[M=4096, N=2048] = A[M,K=2048] * Bt[N,K]^T, bf16 internal.
// 128x128 tile, 4 waves, 16x16x32 MFMA, global_load_lds width 16.
// XOR-swizzled LDS layout. Grid (n, z, m).
// Epilogues: OF!=null -> fp32 natural; z==vz -> bf16 vT; else bf16 natural.
// ---------------------------------------------------------------------------
__global__ __launch_bounds__(256, 4) void gemm_bt_kernel(
    const u16* __restrict__ A,
    const u16* __restrict__ B0, const u16* __restrict__ B1, const u16* __restrict__ B2,
    u16* __restrict__ O0, u16* __restrict__ O1, u16* __restrict__ O2,
    int vz, float* __restrict__ OF) {
  const int z = blockIdx.y;
  const u16* Bt = (z == 0) ? B0 : (z == 1) ? B1 : B2;
  u16*       O  = (z == 0) ? O0 : (z == 1) ? O1 : O2;

  __shared__ u16 As[128 * 64];   // 16 KB, swizzled row-major
  __shared__ u16 Bs[128 * 64];   // 16 KB

  const int tid  = threadIdx.x;
  const int wave = tid >> 6;
  const int lane = tid & 63;
  const int quad = lane >> 4;
  const int l15  = lane & 15;

  const int bm = blockIdx.z * 128;
  const int bn = blockIdx.x * 128;

  const int rlo = lane >> 3;                     // 0..7
  const int swb = ((lane & 7) + rlo) & 7;        // swizzled source block
  const u16* Ag = A  + (size_t)(bm + wave * 32 + rlo) * CDIM + swb * 8;
  const u16* Bg = Bt + (size_t)(bn + wave * 32 + rlo) * CDIM + swb * 8;
  u16* AsW = As + wave * 2048 + lane * 8;
  u16* BsW = Bs + wave * 2048 + lane * 8;

  const f32x4 zero4 = {0.f, 0.f, 0.f, 0.f};
  f32x4 acc[4][4];
#pragma unroll
  for (int mt = 0; mt < 4; ++mt)
#pragma unroll
    for (int nt = 0; nt < 4; ++nt) acc[mt][nt] = zero4;

  const int mh = (wave >> 1) * 64;
  const int nh = (wave & 1) * 64;

  const int off0 = ((quad - l15) & 7) * 8;       // ks = 0
  const int off1 = off0 ^ 32;                    // ks = 1

  for (int kb = 0; kb < CDIM; kb += 64) {
#pragma unroll
    for (int g = 0; g < 4; ++g) {
      gload_lds16(Ag + kb + (size_t)g * 8 * CDIM, AsW + g * 512);
      gload_lds16(Bg + kb + (size_t)g * 8 * CDIM, BsW + g * 512);
    }
    __syncthreads();

#pragma unroll
    for (int ks = 0; ks < 2; ++ks) {
      const int fo = ks ? off1 : off0;
      short8 af[4], bfr[4];
#pragma unroll
      for (int t = 0; t < 4; ++t) {
        af[t]  = *(const short8*)(As + (mh + t * 16 + l15) * 64 + fo);
        bfr[t] = *(const short8*)(Bs + (nh + t * 16 + l15) * 64 + fo);
      }
#pragma unroll
      for (int mt = 0; mt < 4; ++mt)
#pragma unroll
        for (int nt = 0; nt < 4; ++nt)
          acc[mt][nt] = __builtin_amdgcn_mfma_f32_16x16x32_bf16(af[mt], bfr[nt],
                                                                acc[mt][nt], 0, 0, 0);
    }
    __syncthreads();
  }

  if (OF != nullptr) {
#pragma unroll
    for (int mt = 0; mt < 4; ++mt) {
      const int row0 = bm + mh + mt * 16 + quad * 4;
#pragma unroll
      for (int nt = 0; nt < 4; ++nt) {
        const int col = bn + nh + nt * 16 + l15;
#pragma unroll
        for (int r = 0; r < 4; ++r)
          OF[(size_t)(row0 + r) * CDIM + col] = acc[mt][nt][r];
      }
    }
  } else if (z != vz) {
#pragma unroll
    for (int mt = 0; mt < 4; ++mt) {
      const int row0 = bm + mh + mt * 16 + quad * 4;
#pragma unroll
      for (int nt = 0; nt < 4; ++nt) {
        const int col = bn + nh + nt * 16 + l15;
#pragma unroll
        for (int r = 0; r < 4; ++r)
          O[(size_t)(row0 + r) * CDIM + col] = f2bf(acc[mt][nt][r]);
      }
    }
  } else {
    // v epilogue: O = vT[(b*H + head)*D + d][t]; packed 8B store
    const int head = bn >> 7;
#pragma unroll
    for (int mt = 0; mt < 4; ++mt) {
      const int gm0 = bm + mh + mt * 16 + quad * 4;
      const int b  = gm0 >> 11;
      const int t0 = gm0 & (TSEQ - 1);
#pragma unroll
      for (int nt = 0; nt < 4; ++nt) {
        const int d = nh + nt * 16 + l15;
        u16x4 pk;
#pragma unroll
        for (int r = 0; r < 4; ++r) pk[r] = f2bf(acc[mt][nt][r]);
        *(u16x4*)(O + ((size_t)((b * NHEAD + head) * DHEAD + d)) * TSEQ + t0) = pk;
      }
    }
  }
}

// ---------------------------------------------------------------------------
// Flash attention, S^T formulation, 32x32x16 MFMA, in-register softmax.
// R9: chain-shortening, NOT occupancy (R5/R6/R8 proved 4 waves/SIMD either
// spills [oacc[4]+qf > 128-reg cap] or duplicates work). Back to R7's
// 256-thr / 4-wave / 2-blocks-per-CU shape (2 waves/SIMD, 256 regs/wave,
// no spill possible) and attack the ~4300-cyc/iter serial chain:
//  * KVBLK 32 -> 64: barrier-periods halve (56 -> ~28).
//  * QK^T as 4 INDEPENDENT MFMA chains (2 key-subtiles x 2-way split):
//    dep latency ~512 -> ~260 cyc. (+32 v_add to merge; net win if
//    chain-bound.)
//  * softmax/pack width 32 (all independent), PV = 4 independent
//    oacc[dt] chains of 4.
// Kept: XCD remap, gload_lds staging w/ pre-swizzled global source
// (linear LDS dest), XOR chunk swizzles (re-derived for 64-key rows:
// V rows now 8 chunks -> full 3-bit XOR, 2 lanes/bank-quad everywhere),
// tile-skip remap (in 64-key units), in-reg softmax, depth-1 prefetch.
// LDS 64 KB (2 blocks/CU = 128 <= 160). Reg peak ~190 < 256.
// ---------------------------------------------------------------------------
__global__ __launch_bounds__(256, 2) void attn_kernel(
    const u16* __restrict__ q, const u16* __restrict__ k,
    const u16* __restrict__ vT, u16* __restrict__ o) {
  __shared__ u16 ks[2 * 64 * 128];   // [buf][key 64][chan 128], chunk-swizzled
  __shared__ u16 vs[2 * 128 * 64];   // [buf][d 128][key 64], chunk-swizzled

  const int tid  = threadIdx.x;        // 0..255
  const int wave = tid >> 6;           // 0..3 = q-subtile
  const int lane = tid & 63;
  const int hi   = lane >> 5;          // k-half select in 32x32x16 fragments
  const int l31  = lane & 31;

  // XCD-aware remap: xcd = flat%8 owns 4 heads x 16 q-blocks
  // -> 4 MB K/V working set per XCD = one L2.
  const int flat = blockIdx.y * 16 + blockIdx.x;   // [0,512)
  const int qb   = (flat >> 3) & 15;
  const int bh   = (flat & 7) * 4 + (flat >> 7);   // b*16 + h
  const int b    = bh >> 4;
  const int h    = bh & 15;
  const int qw0  = qb * 128 + wave * 32;
  const int qi   = qw0 + l31;          // this lane's q row (col of S^T)

  // Q B-fragments: qf[s] = Q[qi][s*16 + hi*8 .. +8]
  short8 qf[8];
  {
    const u16* qrow = q + ((size_t)(b * TSEQ + qi)) * CDIM + h * DHEAD + hi * 8;
#pragma unroll
    for (int s = 0; s < 8; ++s) qf[s] = *(const short8*)(qrow + s * 16);
  }

  f32x16 oacc[4];   // [dt]: O^T[d = dt*32 + (r&3)+8*(r>>2)+4*hi][q = qi]
#pragma unroll
  for (int dt = 0; dt < 4; ++dt)
#pragma unroll
    for (int r = 0; r < 16; ++r) oacc[dt][r] = 0.f;
  float lrow = 0.f;

  const u16* kbase = k + ((size_t)(b * TSEQ)) * CDIM + h * DHEAD;
  const u16* vbase = vT + ((size_t)bh) * DHEAD * TSEQ;
  const float SC  = 0.08838834764831845f * 1.4426950408889634f; // 1/sqrt(128)*log2e
  const float MSH = 12.0f;   // fixed softmax shift (log2 domain)

  // remap out fully-block-masked 64-key tiles: t in [2qb-6, 2qb-1]
  int tlo = 2 * qb - 6; if (tlo < 0) tlo = 0;
  int nskip = (2 * qb - 1) - tlo + 1; if (nskip < 0) nskip = 0;
  const int nact = 32 - nskip;   // 26..32
  auto jof = [&](int a) { return ((a < tlo) ? a : a + nskip) * 64; };

  // gload_lds staging: per wave 4 K + 4 V gloads per 64-key tile.
  // LDS dest linear (wave base + lane*16); global SOURCE pre-swizzled so
  // LDS[row][c] = X[row][c ^ (row&7)] (16B chunks), matching the reads.
  // K: issue g covers rows w*16+4g..+3 (row&7 same for g and g+2).
  const int krA = wave * 16 + (lane >> 4);             // g=0 row
  const int krB = krA + 4;                             // g=1 row
  const int kc  = lane & 15;
  const u16* kgpA = kbase + (size_t)krA * CDIM + ((kc ^ (krA & 7)) * 8);
  const u16* kgpB = kbase + (size_t)krB * CDIM + ((kc ^ (krB & 7)) * 8);
  // V: rows w*32+8g+(lane>>3); row&7 = (lane>>3)&7 independent of g.
  const int vr  = wave * 32 + (lane >> 3);
  const int vc  = lane & 7;
  const u16* vgp = vbase + (size_t)vr * TSEQ + ((vc ^ (vr & 7)) * 8);
  u16* ksw = ks + (wave * 16) * 128 + lane * 8;        // buf0; buf1 = +8192
  u16* vsw = vs + (wave * 32) * 64 + lane * 8;

  auto stage = [&](int j, int buf) {
    const int off = buf * 8192;
#pragma unroll
    for (int g = 0; g < 4; ++g) {
      const u16* kg = (g & 1) ? kgpB : kgpA;
      gload_lds16(kg + (size_t)(j + (g >> 1) * 8) * CDIM, ksw + off + g * 512);
      gload_lds16(vgp + j + (size_t)(g * 8) * TSEQ, vsw + off + g * 512);
    }
  };

  // prologue: stage tile 0 into buffer 0
  stage(jof(0), 0);
  __syncthreads();

  for (int it = 0; it < nact; ++it) {
    const int p = it & 1;
    const int j0 = jof(it);

    // issue next tile's gloads into the other buffer (hidden under compute;
    // the barrier at loop end drains vmcnt before anyone reads it)
    if (it + 1 < nact) stage(jof(it + 1), 1 - p);

    const u16* ksp = ks + p * 8192;
    const u16* vsp = vs + p * 8192;

    // fully-masked for this wave's 32 q-rows?
    const bool wskip = (j0 + 63 <= qw0) && (j0 >= qw0 + 31 - (WIN - 1));
    if (!wskip) {
      // S^T = K * Q^T: two 32x32 key-subtiles, each via 2 independent
      // accumulator chains (4 chains total, dep depth 4).
      f32x16 sa0, sb0, sa1, sb1;
#pragma unroll
      for (int r = 0; r < 16; ++r) { sa0[r] = 0.f; sb0[r] = 0.f; sa1[r] = 0.f; sb1[r] = 0.f; }
#pragma unroll
      for (int s = 0; s < 8; s += 2) {
        const int c0 = ((s * 2 + hi) ^ (l31 & 7)) * 8;
        const int c1 = (((s + 1) * 2 + hi) ^ (l31 & 7)) * 8;
        const short8 k00 = *(const short8*)(ksp + l31 * 128 + c0);
        const short8 k01 = *(const short8*)(ksp + l31 * 128 + c1);
        const short8 k10 = *(const short8*)(ksp + (32 + l31) * 128 + c0);
        const short8 k11 = *(const short8*)(ksp + (32 + l31) * 128 + c1);
        sa0 = __builtin_amdgcn_mfma_f32_32x32x16_bf16(k00, qf[s],     sa0, 0, 0, 0);
        sb0 = __builtin_amdgcn_mfma_f32_32x32x16_bf16(k01, qf[s + 1], sb0, 0, 0, 0);
        sa1 = __builtin_amdgcn_mfma_f32_32x32x16_bf16(k10, qf[s],     sa1, 0, 0, 0);
        sb1 = __builtin_amdgcn_mfma_f32_32x32x16_bf16(k11, qf[s + 1], sb1, 0, 0, 0);
      }
      const f32x16 sf0 = sa0 + sb0;
      const f32x16 sf1 = sa1 + sb1;

      // softmax numerator for both subtiles (+ mask on band-edge tiles).
      // element r of subtile jt: key = j0 + jt*32 + (r&3)+8*(r>>2)+4*hi.
      float pe0[16], pe1[16];
      const bool hasMask = (qw0 + 31 >= j0) && (qw0 <= j0 + 63 + (WIN - 1));
      if (hasMask) {
#pragma unroll
        for (int r = 0; r < 16; ++r) {
          const int ko = (r & 3) + 8 * (r >> 2) + 4 * hi;
          const int kj0 = j0 + ko, kj1 = j0 + 32 + ko;
          const float e0 = exp2f(fmaf(sf0[r], SC, -MSH));
          const float e1 = exp2f(fmaf(sf1[r], SC, -MSH));
          pe0[r] = ((unsigned)(qi - kj0) < (unsigned)WIN) ? 0.f : e0;
          pe1[r] = ((unsigned)(qi - kj1) < (unsigned)WIN) ? 0.f : e1;
        }
      } else {
#pragma unroll
        for (int r = 0; r < 16; ++r) {
          pe0[r] = exp2f(fmaf(sf0[r], SC, -MSH));
          pe1[r] = exp2f(fmaf(sf1[r], SC, -MSH));
        }
      }
#pragma unroll
      for (int r = 0; r < 16; ++r) lrow += pe0[r] + pe1[r];

      // P -> bf16 PV B-fragments, fully in registers (per subtile:
      // 8x v_cvt_pk_bf16_f32 + 4x v_permlane32_swap_b32).
      short8 pf[2][2];   // [jt][kk]: B[k = jt*32+kk*16 .. +16][q]
#pragma unroll
      for (int jt = 0; jt < 2; ++jt) {
        const float* pe = jt ? pe1 : pe0;
        int D0, D1, D2, D3, D4, D5, D6, D7;
        asm("v_cvt_pk_bf16_f32 %0, %1, %2" : "=v"(D0) : "v"(pe[0]),  "v"(pe[1]));
        asm("v_cvt_pk_bf16_f32 %0, %1, %2" : "=v"(D1) : "v"(pe[2]),  "v"(pe[3]));
        asm("v_cvt_pk_bf16_f32 %0, %1, %2" : "=v"(D2) : "v"(pe[4]),  "v"(pe[5]));
        asm("v_cvt_pk_bf16_f32 %0, %1, %2" : "=v"(D3) : "v"(pe[6]),  "v"(pe[7]));
        asm("v_cvt_pk_bf16_f32 %0, %1, %2" : "=v"(D4) : "v"(pe[8]),  "v"(pe[9]));
        asm("v_cvt_pk_bf16_f32 %0, %1, %2" : "=v"(D5) : "v"(pe[10]), "v"(pe[11]));
        asm("v_cvt_pk_bf16_f32 %0, %1, %2" : "=v"(D6) : "v"(pe[12]), "v"(pe[13]));
        asm("v_cvt_pk_bf16_f32 %0, %1, %2" : "=v"(D7) : "v"(pe[14]), "v"(pe[15]));
        asm("v_permlane32_swap_b32 %0, %1" : "+v"(D0), "+v"(D2));
        asm("v_permlane32_swap_b32 %0, %1" : "+v"(D1), "+v"(D3));
        asm("v_permlane32_swap_b32 %0, %1" : "+v"(D4), "+v"(D6));
        asm("v_permlane32_swap_b32 %0, %1" : "+v"(D5), "+v"(D7));
        union { int i[4]; short8 s8; } u0, u1;
        u0.i[0] = D0; u0.i[1] = D1; u0.i[2] = D2; u0.i[3] = D3;
        u1.i[0] = D4; u1.i[1] = D5; u1.i[2] = D6; u1.i[3] = D7;
        pf[jt][0] = u0.s8;
        pf[jt][1] = u1.s8;
      }

      // O^T += V^T * P^T  (A = V^T rows d; per dt: 4 MFMAs over 64 keys;
      // 4 independent oacc[dt] chains).
#pragma unroll
      for (int dt = 0; dt < 4; ++dt) {
        const u16* vrow = vsp + (dt * 32 + l31) * 64;
        const int sw = (l31 & 7);
#pragma unroll
        for (int jt = 0; jt < 2; ++jt) {
          const short8 vf0 = *(const short8*)(vrow + (((jt * 4 + 0) + hi) ^ sw) * 8);
          const short8 vf1 = *(const short8*)(vrow + (((jt * 4 + 2) + hi) ^ sw) * 8);
          oacc[dt] = __builtin_amdgcn_mfma_f32_32x32x16_bf16(vf0, pf[jt][0], oacc[dt], 0, 0, 0);
          oacc[dt] = __builtin_amdgcn_mfma_f32_32x32x16_bf16(vf1, pf[jt][1], oacc[dt], 0, 0, 0);
        }
      }
    }

    __syncthreads();   // drains vmcnt (prefetch landed) + frees buf p
  }

  // lrow: lanes hi=0/1 hold complementary key subsets for the same q
  lrow += __shfl_xor(lrow, 32, 64);
  const float inv = 1.0f / lrow;

  // O^T[d][q]: reg r of tile dt -> d = dt*32 + 8*(r>>2) + 4*hi + (r&3)
  u16* obase = o + ((size_t)(b * TSEQ + qi)) * CDIM + h * DHEAD;
#pragma unroll
  for (int dt = 0; dt < 4; ++dt)
#pragma unroll
    for (int a2 = 0; a2 < 4; ++a2) {
      u16x4 pkd;
#pragma unroll
      for (int r = 0; r < 4; ++r) pkd[r] = f2bf(oacc[dt][a2 * 4 + r] * inv);
      *(u16x4*)(obase + dt * 32 + a2 * 8 + hi * 4) = pkd;
    }
}

// ---------------------------------------------------------------------------
extern "C" void kernel_launch(void* const* d_in, const int* in_sizes, int n_in,
                              void* d_out, int out_size, void* d_ws, size_t ws_size,
                              hipStream_t stream) {
  (void)in_sizes; (void)n_in; (void)out_size; (void)ws_size;
  const float* x  = (const float*)d_in[0];
  const float* Wq = (const float*)d_in[1];
  const float* Wk = (const float*)d_in[2];
  const float* Wv = (const float*)d_in[3];
  const float* Wo = (const float*)d_in[4];
  float* out = (float*)d_out;

  char* ws = (char*)d_ws;
  const size_t WT = (size_t)CDIM * CDIM * sizeof(u16);   // 8 MiB
  const size_t QS = (size_t)MROWS * CDIM * sizeof(u16);  // 16 MiB
  u16* WqT = (u16*)(ws + 0 * WT);
  u16* WkT = (u16*)(ws + 1 * WT);
  u16* WvT = (u16*)(ws + 2 * WT);
  u16* WoT = (u16*)(ws + 3 * WT);
  u16* xb  = (u16*)(ws + 4 * WT);
  u16* qb  = (u16*)(ws + 4 * WT + 1 * QS);
  u16* kb  = (u16*)(ws + 4 * WT + 2 * QS);
  u16* vTb = (u16*)(ws + 4 * WT + 3 * QS);
  u16* ob  = (u16*)(ws + 4 * WT + 4 * QS);
  float* ct = (float*)(ws + 4 * WT + 5 * QS);
  float* st = ct + TSEQ * 64;

  transpose_kernel<<<dim3(64, 64, 5), dim3(32, 8), 0, stream>>>(
      Wq, Wk, Wv, Wo, WqT, WkT, WvT, WoT, x, xb);
  rope_table_kernel<<<dim3(TSEQ * 64 / 256), 256, 0, stream>>>(ct, st);
  gemm_bt_kernel<<<dim3(16, 3, 32), 256, 0, stream>>>(
      xb, WqT, WkT, WvT, qb, kb, vTb, 2, nullptr);
  rope_apply_kernel<<<dim3(16384, 2), 256, 0, stream>>>(qb, kb, ct, st);
  attn_kernel<<<dim3(16, 32), 256, 0, stream>>>(qb, kb, vTb, ob);
  gemm_bt_kernel<<<dim3(16, 1, 32), 256, 0, stream>>>(
      ob, WoT, WoT, WoT, nullptr, nullptr, nullptr, -1, out);
}